// Round 2
// baseline (558.298 us; speedup 1.0000x reference)
//
#include <hip/hip_runtime.h>

// TransitionUp: segment mean-pool -> linear2+ReLU (tiny) -> broadcast ->
// [x, h[seg]] @ W1 + b1 -> BN(eval) -> ReLU.
//
// Folded math:
//   a[j]     = gamma[j] * rsqrt(run_var[j]+eps)
//   d[j]     = beta[j] - run_mean[j]*a[j]
//   W'[k][j] = W1[k][j] * a[j]                  (k in 0..63, the x-half)
//   bias'[b][j] = (h[b]@W1[64:] + b1)[j]*a[j] + d[j]
//   out[p][j] = relu( x[p]@W'[:,j] + bias'[seg(p)][j] )
//
// R4 restructure: x was read TWICE (pool, then main) = 536 MB of the 804 MB
// floor. z = x@W' does NOT depend on pooling, so:
//   K1: ONE pass over x -> segment sums (from the same register staging)
//       AND z = x@W' stored f16 (134 MB) to workspace. x loads are
//       NONTEMPORAL (x is dead afterwards; keep it out of the LLC).
//       W' computed in-register from W1/gamma/rvar (no prep kernel).
//   K2: bias'[b][j] (tiny).
//   K3: out = relu(z + bias'[seg]): z read regular (128 MiB, LLC-resident
//       candidate), out stored NONTEMPORAL.
// Worst case traffic == today's 804 MB (neutral); if LLC retains z: ~670 MB.

#define MAXB 16

typedef _Float16 half8 __attribute__((ext_vector_type(8)));
typedef float float4v __attribute__((ext_vector_type(4)));

// ---------------------------------------------------------------- kernel 1
// Fused pooling + z = x@W' (f16). Each wave: 128 rows (8 tiles of 16),
// 4 col-tiles. A frag (m89 layout): lane holds A[m=lane&15][k=quad*8+j].
// Pooling: lane accumulates its 16 staged fp32 values over its 8 rows,
// then shfl-reduce over the 16 m-lanes, LDS across 4 waves, atomicAdd.
__global__ __launch_bounds__(256) void fuse_kernel(
    const float* __restrict__ x, const int* __restrict__ o,
    const float* __restrict__ W1, const float* __restrict__ gamma,
    const float* __restrict__ rvar,
    float* __restrict__ gsums, _Float16* __restrict__ z,
    int nB, int ptsPerBlock) {
  __shared__ int so_s[MAXB];
  __shared__ float red[4 * 64];       // cross-wave pooling scratch
  __shared__ float ssum2[MAXB * 64];  // boundary-block bins
  const int tid = threadIdx.x;
  if (tid < nB) so_s[tid] = o[tid];
  __syncthreads();

  const int lane = tid & 63;
  const int m = lane & 15;
  const int quad = lane >> 4;
  const int w = tid >> 6;
  const int p0 = blockIdx.x * ptsPerBlock;
  const int rows0 = p0 + w * 128;

  // B = W' computed in-register: 4 col-tiles x 2 K-halves x 8 f16.
  // W1 is 16 KB -> L1/L2-hot after first blocks; cost amortized over 512 rows.
  half8 bfrag[4][2];
#pragma unroll
  for (int t = 0; t < 4; ++t) {
    const int n = t * 16 + m;
    const float a = gamma[n] * rsqrtf(rvar[n] + 1e-5f);
#pragma unroll
    for (int h = 0; h < 2; ++h)
#pragma unroll
      for (int jj = 0; jj < 8; ++jj)
        bfrag[t][h][jj] = (_Float16)(W1[(h * 32 + quad * 8 + jj) * 64 + n] * a);
  }

  int sFirst = 0;
  while (p0 >= so_s[sFirst]) sFirst++;
  int sLast = sFirst;
  while (p0 + ptsPerBlock - 1 >= so_s[sLast]) sLast++;
  const bool uniform = (sFirst == sLast);

  float4v s0 = {0.f, 0.f, 0.f, 0.f}, s1 = s0, s2 = s0, s3 = s0;  // pooling acc

  float4v f0, f1, f2, f3;  // fp32 staging for one 16x64 A-tile
  {
    const float* p = x + (size_t)(rows0 + m) * 64 + quad * 8;
    f0 = __builtin_nontemporal_load((const float4v*)(p + 0));
    f1 = __builtin_nontemporal_load((const float4v*)(p + 4));
    f2 = __builtin_nontemporal_load((const float4v*)(p + 32));
    f3 = __builtin_nontemporal_load((const float4v*)(p + 36));
  }

  for (int i = 0; i < 8; ++i) {
    const int row0 = rows0 + i * 16;
    s0 += f0; s1 += f1; s2 += f2; s3 += f3;  // pooling (current tile)

    half8 a0, a1;
    a0[0] = (_Float16)f0[0]; a0[1] = (_Float16)f0[1];
    a0[2] = (_Float16)f0[2]; a0[3] = (_Float16)f0[3];
    a0[4] = (_Float16)f1[0]; a0[5] = (_Float16)f1[1];
    a0[6] = (_Float16)f1[2]; a0[7] = (_Float16)f1[3];
    a1[0] = (_Float16)f2[0]; a1[1] = (_Float16)f2[1];
    a1[2] = (_Float16)f2[2]; a1[3] = (_Float16)f2[3];
    a1[4] = (_Float16)f3[0]; a1[5] = (_Float16)f3[1];
    a1[6] = (_Float16)f3[2]; a1[7] = (_Float16)f3[3];

    if (i < 7) {  // prefetch next tile (nontemporal: x is single-use now)
      const float* p = x + (size_t)(row0 + 16 + m) * 64 + quad * 8;
      f0 = __builtin_nontemporal_load((const float4v*)(p + 0));
      f1 = __builtin_nontemporal_load((const float4v*)(p + 4));
      f2 = __builtin_nontemporal_load((const float4v*)(p + 32));
      f3 = __builtin_nontemporal_load((const float4v*)(p + 36));
    }

    // z has no segment dependence: branch-free MFMA + f16 store.
#pragma unroll
    for (int t = 0; t < 4; ++t) {
      float4v c = {0.f, 0.f, 0.f, 0.f};
      c = __builtin_amdgcn_mfma_f32_16x16x32_f16(a0, bfrag[t][0], c, 0, 0, 0);
      c = __builtin_amdgcn_mfma_f32_16x16x32_f16(a1, bfrag[t][1], c, 0, 0, 0);
      _Float16* zp = z + (size_t)(row0 + quad * 4) * 64 + t * 16 + m;
#pragma unroll
      for (int rg = 0; rg < 4; ++rg)
        zp[(size_t)rg * 64] = (_Float16)c[rg];
    }
  }

  if (uniform) {
    // reduce over the 16 m-lanes (lane bits 0..3; stays within quad group)
#pragma unroll
    for (int mask = 1; mask < 16; mask <<= 1) {
#pragma unroll
      for (int k = 0; k < 4; ++k) {
        s0[k] += __shfl_xor(s0[k], mask);
        s1[k] += __shfl_xor(s1[k], mask);
        s2[k] += __shfl_xor(s2[k], mask);
        s3[k] += __shfl_xor(s3[k], mask);
      }
    }
    if (m == 0) {  // lane quad*16: cols quad*8+0..7 and 32+quad*8+0..7
      *(float4v*)&red[w * 64 + quad * 8 + 0] = s0;
      *(float4v*)&red[w * 64 + quad * 8 + 4] = s1;
      *(float4v*)&red[w * 64 + 32 + quad * 8 + 0] = s2;
      *(float4v*)&red[w * 64 + 32 + quad * 8 + 4] = s3;
    }
    __syncthreads();
    if (tid < 64) {
      float s = red[tid] + red[64 + tid] + red[128 + tid] + red[192 + tid];
      atomicAdd(&gsums[sFirst * 64 + tid], s);
    }
  } else {  // boundary block (rare): re-scan rows, per-point binning (L2-hot)
    const int c4 = (tid & 15) * 4;
    const int r  = tid >> 4;
    const int iters = ptsPerBlock >> 4;
    for (int i = tid; i < nB * 64; i += 256) ssum2[i] = 0.f;
    __syncthreads();
    for (int i = 0; i < iters; ++i) {
      int p = p0 + i * 16 + r;
      int s = 0;
      while (p >= so_s[s]) s++;
      float4v v = *(const float4v*)(x + (size_t)p * 64 + c4);
      atomicAdd(&ssum2[s * 64 + c4 + 0], v[0]);
      atomicAdd(&ssum2[s * 64 + c4 + 1], v[1]);
      atomicAdd(&ssum2[s * 64 + c4 + 2], v[2]);
      atomicAdd(&ssum2[s * 64 + c4 + 3], v[3]);
    }
    __syncthreads();
    for (int i = tid; i < nB * 64; i += 256) {
      float v = ssum2[i];
      if (v != 0.f) atomicAdd(&gsums[i], v);
    }
  }
}

// ---------------------------------------------------------------- kernel 2
// mean -> h = relu(mean@W2+b2) -> bias'[b][j].
__global__ __launch_bounds__(256) void mid_kernel(
    const float* __restrict__ gsums, const int* __restrict__ o,
    const float* __restrict__ W2, const float* __restrict__ b2,
    const float* __restrict__ W1, const float* __restrict__ b1,
    const float* __restrict__ gamma, const float* __restrict__ beta,
    const float* __restrict__ rmean, const float* __restrict__ rvar,
    float* __restrict__ biasp, int nB) {
  __shared__ float smean[MAXB * 64];
  __shared__ float sh[MAXB * 64];
  const int tid = threadIdx.x;
  const int j = tid & 63;
  const int bq = tid >> 6;

  for (int i = tid; i < nB * 64; i += 256) {
    int b = i >> 6;
    int cnt = o[b] - (b ? o[b - 1] : 0);
    smean[i] = gsums[i] / (float)cnt;
  }
  __syncthreads();

  for (int b = bq; b < nB; b += 4) {
    float p0 = 0.f, p1 = 0.f, p2 = 0.f, p3 = 0.f;
#pragma unroll
    for (int c = 0; c < 64; c += 4) {
      p0 = fmaf(smean[b * 64 + c + 0], W2[(c + 0) * 64 + j], p0);
      p1 = fmaf(smean[b * 64 + c + 1], W2[(c + 1) * 64 + j], p1);
      p2 = fmaf(smean[b * 64 + c + 2], W2[(c + 2) * 64 + j], p2);
      p3 = fmaf(smean[b * 64 + c + 3], W2[(c + 3) * 64 + j], p3);
    }
    sh[b * 64 + j] = fmaxf(((p0 + p1) + (p2 + p3)) + b2[j], 0.f);
  }
  __syncthreads();

  const float a = gamma[j] * rsqrtf(rvar[j] + 1e-5f);
  const float d = beta[j] - rmean[j] * a;
  for (int b = bq; b < nB; b += 4) {
    float p0 = 0.f, p1 = 0.f, p2 = 0.f, p3 = 0.f;
#pragma unroll
    for (int c = 0; c < 64; c += 4) {
      p0 = fmaf(sh[b * 64 + c + 0], W1[(64 + c + 0) * 64 + j], p0);
      p1 = fmaf(sh[b * 64 + c + 1], W1[(64 + c + 1) * 64 + j], p1);
      p2 = fmaf(sh[b * 64 + c + 2], W1[(64 + c + 2) * 64 + j], p2);
      p3 = fmaf(sh[b * 64 + c + 3], W1[(64 + c + 3) * 64 + j], p3);
    }
    biasp[b * 64 + j] = (((p0 + p1) + (p2 + p3)) + b1[j]) * a + d;
  }
}

// ---------------------------------------------------------------- kernel 3
// out = relu(z + bias'[seg]). z read regular (LLC-resident candidate),
// out nontemporal. Thread = (row stripe, 8-col group); fully coalesced.
__global__ __launch_bounds__(256) void bias_kernel(
    const _Float16* __restrict__ z, const int* __restrict__ o,
    const float* __restrict__ biasp, float* __restrict__ out,
    int nB, int rowsPerBlock) {
  __shared__ int so_s[MAXB];
  const int tid = threadIdx.x;
  if (tid < nB) so_s[tid] = o[tid];
  __syncthreads();

  const int c8 = (tid & 7) * 8;  // 8 consecutive cols per thread
  const int rr = tid >> 3;       // 32 rows per block-iteration
  const int p0 = blockIdx.x * rowsPerBlock;
  const int iters = rowsPerBlock >> 5;

  int sFirst = 0;
  while (p0 >= so_s[sFirst]) sFirst++;
  int sLast = sFirst;
  while (p0 + rowsPerBlock - 1 >= so_s[sLast]) sLast++;

  if (sFirst == sLast) {  // block-uniform (common): bias hoisted to regs
    const float4v b0 = *(const float4v*)(biasp + sFirst * 64 + c8);
    const float4v b1 = *(const float4v*)(biasp + sFirst * 64 + c8 + 4);
#pragma unroll 4
    for (int i = 0; i < iters; ++i) {
      const int row = p0 + i * 32 + rr;
      half8 v = *(const half8*)(z + (size_t)row * 64 + c8);
      float4v r0, r1;
      r0[0] = fmaxf((float)v[0] + b0[0], 0.f);
      r0[1] = fmaxf((float)v[1] + b0[1], 0.f);
      r0[2] = fmaxf((float)v[2] + b0[2], 0.f);
      r0[3] = fmaxf((float)v[3] + b0[3], 0.f);
      r1[0] = fmaxf((float)v[4] + b1[0], 0.f);
      r1[1] = fmaxf((float)v[5] + b1[1], 0.f);
      r1[2] = fmaxf((float)v[6] + b1[2], 0.f);
      r1[3] = fmaxf((float)v[7] + b1[3], 0.f);
      float* op = out + (size_t)row * 64 + c8;
      __builtin_nontemporal_store(r0, (float4v*)(op + 0));
      __builtin_nontemporal_store(r1, (float4v*)(op + 4));
    }
  } else {  // boundary block (rare): per-row segment scan
    for (int i = 0; i < iters; ++i) {
      const int row = p0 + i * 32 + rr;
      int s = 0;
      for (int q = 0; q < nB; ++q) s += (row >= so_s[q]) ? 1 : 0;
      const float4v b0 = *(const float4v*)(biasp + s * 64 + c8);
      const float4v b1 = *(const float4v*)(biasp + s * 64 + c8 + 4);
      half8 v = *(const half8*)(z + (size_t)row * 64 + c8);
      float4v r0, r1;
      r0[0] = fmaxf((float)v[0] + b0[0], 0.f);
      r0[1] = fmaxf((float)v[1] + b0[1], 0.f);
      r0[2] = fmaxf((float)v[2] + b0[2], 0.f);
      r0[3] = fmaxf((float)v[3] + b0[3], 0.f);
      r1[0] = fmaxf((float)v[4] + b1[0], 0.f);
      r1[1] = fmaxf((float)v[5] + b1[1], 0.f);
      r1[2] = fmaxf((float)v[6] + b1[2], 0.f);
      r1[3] = fmaxf((float)v[7] + b1[3], 0.f);
      float* op = out + (size_t)row * 64 + c8;
      __builtin_nontemporal_store(r0, (float4v*)(op + 0));
      __builtin_nontemporal_store(r1, (float4v*)(op + 4));
    }
  }
}

// ---------------------------------------------------------------- launch
extern "C" void kernel_launch(void* const* d_in, const int* in_sizes, int n_in,
                              void* d_out, int out_size, void* d_ws, size_t ws_size,
                              hipStream_t stream) {
  const float* x     = (const float*)d_in[0];
  const int*   o     = (const int*)d_in[1];
  const float* W2    = (const float*)d_in[2];
  const float* b2    = (const float*)d_in[3];
  const float* W1    = (const float*)d_in[4];
  const float* b1    = (const float*)d_in[5];
  const float* gamma = (const float*)d_in[6];
  const float* beta  = (const float*)d_in[7];
  const float* rmean = (const float*)d_in[8];
  const float* rvar  = (const float*)d_in[9];
  float* out = (float*)d_out;

  const int npts = in_sizes[0] / 64;
  const int nB   = in_sizes[1];

  float*    gsums = (float*)d_ws;                    // [16*64] f32
  float*    biasp = gsums + MAXB * 64;               // [16*64] f32
  _Float16* z     = (_Float16*)((char*)d_ws + 8192); // [npts*64] f16 (134 MB)

  hipMemsetAsync(gsums, 0, MAXB * 64 * sizeof(float), stream);

  const int blocks = 2048;  // 512 pts/block at N=1M
  fuse_kernel<<<blocks, 256, 0, stream>>>(x, o, W1, gamma, rvar, gsums, z,
                                          nB, npts / blocks);
  mid_kernel<<<1, 256, 0, stream>>>(gsums, o, W2, b2, W1, b1, gamma, beta,
                                    rmean, rvar, biasp, nB);
  bias_kernel<<<blocks, 256, 0, stream>>>(z, o, biasp, out, nB, npts / blocks);
}